// Round 17
// baseline (118.370 us; speedup 1.0000x reference)
//
#include <hip/hip_runtime.h>
#include <hip/hip_bf16.h>

typedef __bf16 bf16;
typedef __attribute__((ext_vector_type(8))) __bf16 bf16x8;
typedef __attribute__((ext_vector_type(4))) __bf16 bf16x4;
typedef __attribute__((ext_vector_type(4))) float f32x4;

static constexpr int NSEQ = 4;
static constexpr int LQ   = 512;
static constexpr int HQN  = 32;
static constexpr int HKVN = 8;
static constexpr int GQ   = 4;
static constexpr int DH   = 128;
static constexpr int BPS  = 64;     // blocks per sequence (2048/32)
static constexpr int SKV  = 2048;   // max kv length
static constexpr int KVB  = 64;     // kv tile (2 paged blocks)
static constexpr int QBL  = 32;     // l-rows per workgroup (per wave, 1 g head each)
static constexpr int VST  = 72;     // V LDS row stride (elems)

__device__ __forceinline__ bf16x8 cvt8(const float4& a, const float4& b) {
  bf16x8 o;
  o[0] = (bf16)a.x; o[1] = (bf16)a.y; o[2] = (bf16)a.z; o[3] = (bf16)a.w;
  o[4] = (bf16)b.x; o[5] = (bf16)b.y; o[6] = (bf16)b.z; o[7] = (bf16)b.w;
  return o;
}

// merged prepass (single dispatch): blocks [0,4096) gather+convert K into
// kb[b][h][s][d]; blocks [4096,5120) gather+convert+transpose V into
// vt[b][h][d][s]. Disjoint outputs, independent work.
__global__ void prep_kv(const float* __restrict__ kc, const float* __restrict__ vc,
                        const int* __restrict__ bt, bf16* __restrict__ kb,
                        bf16* __restrict__ vt) {
  int blk = (int)blockIdx.x;
  int tid = (int)threadIdx.x;
  if (blk < 4096) {
    // ---- K: pure gather + f32->bf16 ----
    int e = (blk * 256 + tid) * 8;
    int d = e & 127;
    int s = (e >> 7) & 2047;
    int h = (e >> 18) & 7;
    int b = e >> 21;
    int pb = bt[b * BPS + (s >> 5)];
    const float* src = kc + (((size_t)pb * 32 + (s & 31)) * 8 + h) * 128 + d;
    float4 a = *(const float4*)src;
    float4 c = *(const float4*)(src + 4);
    *(bf16x8*)(kb + e) = cvt8(a, c);
  } else {
    // ---- V: gather + convert + transpose via LDS tile ----
    __shared__ __align__(16) bf16 T[64][136];
    int bid = blk - 4096;          // 0..1023
    int st = bid & 31;
    int h  = (bid >> 5) & 7;
    int b  = bid >> 8;
    {
      int s  = tid >> 2;
      int d0 = (tid & 3) * 32;
      int sg = st * 64 + s;
      int pb = bt[b * BPS + (sg >> 5)];
      const float* src = vc + (((size_t)pb * 32 + (sg & 31)) * 8 + h) * 128 + d0;
#pragma unroll
      for (int k = 0; k < 4; ++k) {
        float4 a = *(const float4*)(src + 8 * k);
        float4 c = *(const float4*)(src + 8 * k + 4);
        *(bf16x8*)&T[s][d0 + 8 * k] = cvt8(a, c);
      }
    }
    __syncthreads();
    {
      int d  = tid & 127;
      int g2 = tid >> 7;
      bf16* dst = vt + (((size_t)(b * 8 + h)) * 128 + d) * SKV + st * 64 + g2 * 32;
#pragma unroll
      for (int k = 0; k < 4; ++k) {
        bf16x8 o;
#pragma unroll
        for (int j = 0; j < 8; ++j) o[j] = T[g2 * 32 + k * 8 + j][d];
        *(bf16x8*)(dst + 8 * k) = o;
      }
    }
  }
}

// flash attention (R15 verbatim — measured optimum of the explored space):
// 1 workgroup = (b, h, 32 l-rows); wave w = GQA head g = w. Swapped QK^T
// (A=K, B=Q, 16x16x32) -> S^T fragment; softmax in-register (defer-max T13);
// PV via k-PERMUTED 16x16x32 MFMA: the same k-slot permutation pi on A and B
// leaves the contraction invariant; pi is picked so the A-fragment equals the
// values already in accS (plain f32->bf16 cast, zero cross-lane). V LDS uses
// an XOR granule swizzle (T2). Double-buffered K/V, one barrier/tile (T14).
// setprio around MFMA (T5): +4% on THIS structure (R9 vs R14 A/B).
// 2 waves/SIMD is the measured stable operating point (R8/R11/R12/R13 all
// regressed trying to exceed it: staging-doubling / spill / spill / conflicts).
// Softmax kept in R9's serial form (R16's chain-split A/B: neutral/-1%).
template <bool WS>
__global__ __launch_bounds__(256, 2)
void attn_kern(const float* __restrict__ q, const float* __restrict__ kc,
               const float* __restrict__ vc, const int* __restrict__ bt,
               const int* __restrict__ seq_lens, const bf16* __restrict__ kb,
               const bf16* __restrict__ vtb, float* __restrict__ out) {
  __shared__ __align__(16) bf16 Kl[2][64][136];        // [buf][s][d]
  __shared__ __align__(16) bf16 Vl[2][128 * VST];      // [buf][d][s] swizzled

  // bid mapping: bid & bid+256 are complementary qtiles (work sum const),
  // 4 (b,h) combos per XCD residue for L2 locality.
  int bid = (int)blockIdx.x;
  int hi  = bid >> 8;
  int u   = bid & 255;
  int xcd = u & 7;
  int k2  = u >> 3;
  int c   = (k2 >> 3) | (xcd << 2);
  int i   = k2 & 7;
  int qt  = hi ? (15 - i) : i;
  int h   = c & 7;
  int b   = c >> 3;
  int lb  = qt * QBL;

  int tid  = (int)threadIdx.x;
  int w    = tid >> 6;
  int lane = tid & 63;
  int lq   = lane & 15;
  int lg   = lane >> 4;

  int ctx = seq_lens[b] - LQ;
  int nt  = (ctx + lb + QBL + KVB - 1) / KVB;

  const float CEXP = 0.08838834764831843f * 1.44269504088896340f;
  const float TH8  = 8.0f / CEXP;

  // Q fragments (B-operand): lane holds Q[lb + n*16 + lq][kk*32 + lg*8 + j]
  int hq = h * GQ + w;
  bf16x8 qf[2][4];
#pragma unroll
  for (int n = 0; n < 2; ++n) {
    const float* qp = q + (((size_t)(b * LQ + lb + n * 16 + lq)) * HQN + hq) * DH + lg * 8;
#pragma unroll
    for (int kk = 0; kk < 4; ++kk) {
      float4 a = *(const float4*)(qp + kk * 32);
      float4 c2 = *(const float4*)(qp + kk * 32 + 4);
      qf[n][kk] = cvt8(a, c2);
    }
  }

  f32x4 accO[2][8];
  f32x4 zero = {0.f, 0.f, 0.f, 0.f};
#pragma unroll
  for (int m = 0; m < 2; ++m)
#pragma unroll
    for (int nd = 0; nd < 8; ++nd) accO[m][nd] = zero;
  float mrun[2] = {-1e30f, -1e30f};
  float lrun[2] = {0.f, 0.f};

  const int* btr = bt + b * BPS;
  const bf16* kbase = WS ? kb  + (size_t)(b * 8 + h) * SKV * DH : nullptr;
  const bf16* vbase = WS ? vtb + (size_t)(b * 8 + h) * DH * SKV : nullptr;

  // staging geometry
  int ks_ = tid >> 2, kd0 = (tid & 3) * 32;   // K: [s][d] rows
  int vd_ = tid >> 1, vu  = tid & 1;          // V^T: [d][s] rows, col half
  int vxw = ((vd_ >> 3) & 3) << 1;            // write-side granule XOR

  bf16x8 kpre[4], vpre[4];
  auto ldKV = [&](int t) {
    const bf16* ks = kbase + ((size_t)t * 64 + ks_) * DH + kd0;
#pragma unroll
    for (int k = 0; k < 4; ++k) kpre[k] = *(const bf16x8*)(ks + 8 * k);
    const bf16* vs = vbase + (size_t)vd_ * SKV + t * 64 + vu * 32;
#pragma unroll
    for (int k = 0; k < 4; ++k) vpre[k] = *(const bf16x8*)(vs + 8 * k);
  };
  auto stKV = [&](int bb) {
#pragma unroll
    for (int k = 0; k < 4; ++k) *(bf16x8*)&Kl[bb][ks_][kd0 + 8 * k] = kpre[k];
#pragma unroll
    for (int k = 0; k < 4; ++k) {
      int g = (4 * vu + k) ^ vxw;             // swizzled 8-elem granule
      *(bf16x8*)&Vl[bb][vd_ * VST + (g << 3)] = vpre[k];
    }
  };

  auto compute = [&](int t, int bb) {
    // ---- QK^T (swapped): S^T rows s = t*64+m*16+lg*4+r, col q = n*16+lq ----
    f32x4 accS[4][2];
#pragma unroll
    for (int m = 0; m < 4; ++m)
#pragma unroll
      for (int n = 0; n < 2; ++n) accS[m][n] = zero;
    __builtin_amdgcn_s_setprio(1);
#pragma unroll
    for (int m = 0; m < 4; ++m) {
      bf16x8 ak[4];
#pragma unroll
      for (int kk = 0; kk < 4; ++kk)
        ak[kk] = *(const bf16x8*)&Kl[bb][m * 16 + lq][kk * 32 + lg * 8];
#pragma unroll
      for (int n = 0; n < 2; ++n)
#pragma unroll
        for (int kk = 0; kk < 4; ++kk)
          accS[m][n] = __builtin_amdgcn_mfma_f32_16x16x32_bf16(ak[kk], qf[n][kk], accS[m][n], 0, 0, 0);
    }
    __builtin_amdgcn_s_setprio(0);

    // ---- causal mask (boundary tiles only) ----
    if (t * KVB + KVB - 1 > ctx + lb) {
#pragma unroll
      for (int m = 0; m < 4; ++m) {
        int sg = t * 64 + m * 16 + lg * 4;
#pragma unroll
        for (int n = 0; n < 2; ++n) {
          int qpos = ctx + lb + n * 16 + lq;
#pragma unroll
          for (int r = 0; r < 4; ++r)
            if (sg + r > qpos) accS[m][n][r] = -1e30f;
        }
      }
    }

    // ---- online softmax (per q column = lane&15), defer-max ----
#pragma unroll
    for (int n = 0; n < 2; ++n) {
      float mx = accS[0][n][0];
#pragma unroll
      for (int m = 0; m < 4; ++m)
#pragma unroll
        for (int r = 0; r < 4; ++r) mx = fmaxf(mx, accS[m][n][r]);
      mx = fmaxf(mx, __shfl_xor(mx, 16));
      mx = fmaxf(mx, __shfl_xor(mx, 32));
      if (!__all(mx <= mrun[n] + TH8)) {
        float mnew = fmaxf(mrun[n], mx);
        float corr = exp2f((mrun[n] - mnew) * CEXP);
        mrun[n] = mnew;
        lrun[n] *= corr;
        float cb[4];
#pragma unroll
        for (int r = 0; r < 4; ++r) cb[r] = __shfl(corr, lg * 4 + r);
#pragma unroll
        for (int nd = 0; nd < 8; ++nd)
#pragma unroll
          for (int r = 0; r < 4; ++r) accO[n][nd][r] *= cb[r];
      }
      float psum = 0.f;
#pragma unroll
      for (int m = 0; m < 4; ++m)
#pragma unroll
        for (int r = 0; r < 4; ++r) {
          float p = exp2f((accS[m][n][r] - mrun[n]) * CEXP);
          psum += p;
          accS[m][n][r] = p;
        }
      lrun[n] += psum;
    }

    // ---- k-permuted A-fragment: slot j of (n,ks) holds
    // P[s = 32ks + 16(j>>2) + 4lg + (j&3)] = accS[2ks + (j>>2)][n][j&3]. ----
    bf16x8 ap[2][2];
#pragma unroll
    for (int n = 0; n < 2; ++n)
#pragma unroll
      for (int ks3 = 0; ks3 < 2; ++ks3) {
#pragma unroll
        for (int e = 0; e < 4; ++e) {
          ap[n][ks3][e]     = (bf16)accS[2 * ks3][n][e];
          ap[n][ks3][4 + e] = (bf16)accS[2 * ks3 + 1][n][e];
        }
      }

    // ---- PV: B slot j of ks = V[s=pi(k)][d], read from swizzled Vl ----
    __builtin_amdgcn_s_setprio(1);
#pragma unroll
    for (int nd = 0; nd < 8; ++nd) {
      int d   = nd * 16 + lq;
      int vxr = ((d >> 3) & 3) << 1;
      int rb  = d * VST + 4 * (lg & 1);
#pragma unroll
      for (int ks3 = 0; ks3 < 2; ++ks3) {
        int g0 = 4 * ks3 + (lg >> 1);
        bf16x4 lo = *(const bf16x4*)&Vl[bb][rb + ((g0 ^ vxr) << 3)];
        bf16x4 hi2 = *(const bf16x4*)&Vl[bb][rb + (((g0 + 2) ^ vxr) << 3)];
        bf16x8 bv;
#pragma unroll
        for (int e = 0; e < 4; ++e) { bv[e] = lo[e]; bv[4 + e] = hi2[e]; }
#pragma unroll
        for (int n = 0; n < 2; ++n)
          accO[n][nd] = __builtin_amdgcn_mfma_f32_16x16x32_bf16(ap[n][ks3], bv, accO[n][nd], 0, 0, 0);
      }
    }
    __builtin_amdgcn_s_setprio(0);
  };

  if (WS) {
    ldKV(0);
    stKV(0);
    if (nt > 1) ldKV(1);
    __syncthreads();
    for (int t = 0; t < nt; ++t) {
      int cur = t & 1;
      if (t + 1 < nt) {
        stKV(cur ^ 1);                 // store t+1 (loads issued last iter)
        if (t + 2 < nt) ldKV(t + 2);
      }
      compute(t, cur);
      __syncthreads();                 // single barrier per tile
    }
  } else {
    for (int t = 0; t < nt; ++t) {
      {
        int s  = tid >> 2;
        int d0 = (tid & 3) * 32;
        int pb = btr[t * 2 + (s >> 5)];
        const float* ksrc = kc + (((size_t)pb * 32 + (s & 31)) * 8 + h) * 128 + d0;
#pragma unroll
        for (int k = 0; k < 4; ++k) {
          float4 a = *(const float4*)(ksrc + 8 * k);
          float4 c2 = *(const float4*)(ksrc + 8 * k + 4);
          *(bf16x8*)&Kl[0][s][d0 + 8 * k] = cvt8(a, c2);
        }
        int d  = tid & 127;
        int sh = tid >> 7;
        int vxf = ((d >> 3) & 3) << 1;
        int pbv = btr[t * 2 + sh];
        const float* vsrc = vc + (((size_t)pbv * 32) * 8 + h) * 128 + d;
#pragma unroll
        for (int k = 0; k < 8; ++k) {
          bf16x4 o;
#pragma unroll
          for (int j = 0; j < 4; ++j) o[j] = (bf16)vsrc[(size_t)(k * 4 + j) * 1024];
          int g = (4 * sh + (k >> 1)) ^ vxf;
          *(bf16x4*)&Vl[0][d * VST + (g << 3) + 4 * (k & 1)] = o;
        }
      }
      __syncthreads();
      compute(t, 0);
      __syncthreads();
    }
  }

  // ---- epilogue: finish row sums, normalize, store f32 ----
#pragma unroll
  for (int n = 0; n < 2; ++n) {
    lrun[n] += __shfl_xor(lrun[n], 16);
    lrun[n] += __shfl_xor(lrun[n], 32);
    lrun[n] = 1.f / lrun[n];
  }
#pragma unroll
  for (int m2 = 0; m2 < 2; ++m2) {
    float rb[4];
#pragma unroll
    for (int r = 0; r < 4; ++r) rb[r] = __shfl(lrun[m2], lg * 4 + r);
#pragma unroll
    for (int r = 0; r < 4; ++r) {
      float* op = out + (((size_t)(b * LQ + lb + m2 * 16 + lg * 4 + r)) * HQN + hq) * DH + lq;
#pragma unroll
      for (int nd = 0; nd < 8; ++nd) op[nd * 16] = accO[m2][nd][r] * rb[r];
    }
  }
}

extern "C" void kernel_launch(void* const* d_in, const int* in_sizes, int n_in,
                              void* d_out, int out_size, void* d_ws, size_t ws_size,
                              hipStream_t stream) {
  const float* q  = (const float*)d_in[0];
  const float* kc = (const float*)d_in[1];
  const float* vc = (const float*)d_in[2];
  const int* bt   = (const int*)d_in[3];
  const int* sl   = (const int*)d_in[4];
  float* out = (float*)d_out;

  size_t half = (size_t)NSEQ * HKVN * SKV * DH;
  size_t need = 2 * half * sizeof(bf16);
  if (ws_size >= need) {
    bf16* kb = (bf16*)d_ws;
    bf16* vt = kb + half;
    hipLaunchKernelGGL(prep_kv, dim3(5120), dim3(256), 0, stream, kc, vc, bt, kb, vt);
    hipLaunchKernelGGL((attn_kern<true>), dim3(512), dim3(256), 0, stream,
                       q, kc, vc, bt, sl, kb, vt, out);
  } else {
    hipLaunchKernelGGL((attn_kern<false>), dim3(512), dim3(256), 0, stream,
                       q, kc, vc, bt, sl, (const bf16*)nullptr, (const bf16*)nullptr, out);
  }
}

// Round 18
// 116.411 us; speedup vs baseline: 1.0168x; 1.0168x over previous
//
#include <hip/hip_runtime.h>
#include <hip/hip_bf16.h>

typedef __bf16 bf16;
typedef __attribute__((ext_vector_type(8))) __bf16 bf16x8;
typedef __attribute__((ext_vector_type(4))) __bf16 bf16x4;
typedef __attribute__((ext_vector_type(4))) float f32x4;

static constexpr int NSEQ = 4;
static constexpr int LQ   = 512;
static constexpr int HQN  = 32;
static constexpr int HKVN = 8;
static constexpr int GQ   = 4;
static constexpr int DH   = 128;
static constexpr int BPS  = 64;     // blocks per sequence (2048/32)
static constexpr int SKV  = 2048;   // max kv length
static constexpr int KVB  = 64;     // kv tile (2 paged blocks)
static constexpr int QBL  = 32;     // l-rows per workgroup (per wave, 1 g head each)
static constexpr int VST  = 72;     // V LDS row stride (elems)

__device__ __forceinline__ bf16x8 cvt8(const float4& a, const float4& b) {
  bf16x8 o;
  o[0] = (bf16)a.x; o[1] = (bf16)a.y; o[2] = (bf16)a.z; o[3] = (bf16)a.w;
  o[4] = (bf16)b.x; o[5] = (bf16)b.y; o[6] = (bf16)b.z; o[7] = (bf16)b.w;
  return o;
}

// prepass 1: gather paged K + convert to bf16: kb[b][h][s][d]
__global__ void prep_k(const float* __restrict__ kc, const int* __restrict__ bt,
                       bf16* __restrict__ kb) {
  int e = (blockIdx.x * 256 + threadIdx.x) * 8;
  int d = e & 127;
  int s = (e >> 7) & 2047;
  int h = (e >> 18) & 7;
  int b = e >> 21;
  int pb = bt[b * BPS + (s >> 5)];
  const float* src = kc + (((size_t)pb * 32 + (s & 31)) * 8 + h) * 128 + d;
  float4 a = *(const float4*)src;
  float4 c = *(const float4*)(src + 4);
  *(bf16x8*)(kb + e) = cvt8(a, c);
}

// prepass 2: gather paged V + convert + transpose: vt[b][h][d][s]
__global__ void prep_vt(const float* __restrict__ vc, const int* __restrict__ bt,
                        bf16* __restrict__ vt) {
  __shared__ __align__(16) bf16 T[64][136];
  int bid = blockIdx.x;
  int st = bid & 31;
  int h  = (bid >> 5) & 7;
  int b  = bid >> 8;
  int tid = threadIdx.x;
  {
    int s  = tid >> 2;
    int d0 = (tid & 3) * 32;
    int sg = st * 64 + s;
    int pb = bt[b * BPS + (sg >> 5)];
    const float* src = vc + (((size_t)pb * 32 + (sg & 31)) * 8 + h) * 128 + d0;
#pragma unroll
    for (int k = 0; k < 4; ++k) {
      float4 a = *(const float4*)(src + 8 * k);
      float4 c = *(const float4*)(src + 8 * k + 4);
      *(bf16x8*)&T[s][d0 + 8 * k] = cvt8(a, c);
    }
  }
  __syncthreads();
  {
    int d  = tid & 127;
    int g2 = tid >> 7;
    bf16* dst = vt + (((size_t)(b * 8 + h)) * 128 + d) * SKV + st * 64 + g2 * 32;
#pragma unroll
    for (int k = 0; k < 4; ++k) {
      bf16x8 o;
#pragma unroll
      for (int j = 0; j < 8; ++j) o[j] = T[g2 * 32 + k * 8 + j][d];
      *(bf16x8*)(dst + 8 * k) = o;
    }
  }
}

// flash attention (R15 verbatim — measured optimum of the explored space):
// 1 workgroup = (b, h, 32 l-rows); wave w = GQA head g = w. Swapped QK^T
// (A=K, B=Q, 16x16x32) -> S^T fragment; softmax in-register (defer-max T13);
// PV via k-PERMUTED 16x16x32 MFMA: the same k-slot permutation pi on A and B
// leaves the contraction invariant; pi is picked so the A-fragment equals the
// values already in accS (plain f32->bf16 cast, zero cross-lane). V LDS uses
// an XOR granule swizzle (T2). Double-buffered K/V, one barrier/tile (T14).
// setprio around MFMA (T5): +4% on THIS structure (R9 vs R14 A/B).
// 2 waves/SIMD is the measured stable operating point (R8/R11/R12/R13 all
// regressed trying to exceed it: staging-doubling / spill / spill / conflicts).
// Softmax in R9's serial form (R16 chain-split A/B: -1%); prepasses kept as
// two dispatches (R17 merge A/B: -1.5%).
template <bool WS>
__global__ __launch_bounds__(256, 2)
void attn_kern(const float* __restrict__ q, const float* __restrict__ kc,
               const float* __restrict__ vc, const int* __restrict__ bt,
               const int* __restrict__ seq_lens, const bf16* __restrict__ kb,
               const bf16* __restrict__ vtb, float* __restrict__ out) {
  __shared__ __align__(16) bf16 Kl[2][64][136];        // [buf][s][d]
  __shared__ __align__(16) bf16 Vl[2][128 * VST];      // [buf][d][s] swizzled

  // bid mapping: bid & bid+256 are complementary qtiles (work sum const),
  // 4 (b,h) combos per XCD residue for L2 locality.
  int bid = (int)blockIdx.x;
  int hi  = bid >> 8;
  int u   = bid & 255;
  int xcd = u & 7;
  int k2  = u >> 3;
  int c   = (k2 >> 3) | (xcd << 2);
  int i   = k2 & 7;
  int qt  = hi ? (15 - i) : i;
  int h   = c & 7;
  int b   = c >> 3;
  int lb  = qt * QBL;

  int tid  = (int)threadIdx.x;
  int w    = tid >> 6;
  int lane = tid & 63;
  int lq   = lane & 15;
  int lg   = lane >> 4;

  int ctx = seq_lens[b] - LQ;
  int nt  = (ctx + lb + QBL + KVB - 1) / KVB;

  const float CEXP = 0.08838834764831843f * 1.44269504088896340f;
  const float TH8  = 8.0f / CEXP;

  // Q fragments (B-operand): lane holds Q[lb + n*16 + lq][kk*32 + lg*8 + j]
  int hq = h * GQ + w;
  bf16x8 qf[2][4];
#pragma unroll
  for (int n = 0; n < 2; ++n) {
    const float* qp = q + (((size_t)(b * LQ + lb + n * 16 + lq)) * HQN + hq) * DH + lg * 8;
#pragma unroll
    for (int kk = 0; kk < 4; ++kk) {
      float4 a = *(const float4*)(qp + kk * 32);
      float4 c2 = *(const float4*)(qp + kk * 32 + 4);
      qf[n][kk] = cvt8(a, c2);
    }
  }

  f32x4 accO[2][8];
  f32x4 zero = {0.f, 0.f, 0.f, 0.f};
#pragma unroll
  for (int m = 0; m < 2; ++m)
#pragma unroll
    for (int nd = 0; nd < 8; ++nd) accO[m][nd] = zero;
  float mrun[2] = {-1e30f, -1e30f};
  float lrun[2] = {0.f, 0.f};

  const int* btr = bt + b * BPS;
  const bf16* kbase = WS ? kb  + (size_t)(b * 8 + h) * SKV * DH : nullptr;
  const bf16* vbase = WS ? vtb + (size_t)(b * 8 + h) * DH * SKV : nullptr;

  // staging geometry
  int ks_ = tid >> 2, kd0 = (tid & 3) * 32;   // K: [s][d] rows
  int vd_ = tid >> 1, vu  = tid & 1;          // V^T: [d][s] rows, col half
  int vxw = ((vd_ >> 3) & 3) << 1;            // write-side granule XOR

  bf16x8 kpre[4], vpre[4];
  auto ldKV = [&](int t) {
    const bf16* ks = kbase + ((size_t)t * 64 + ks_) * DH + kd0;
#pragma unroll
    for (int k = 0; k < 4; ++k) kpre[k] = *(const bf16x8*)(ks + 8 * k);
    const bf16* vs = vbase + (size_t)vd_ * SKV + t * 64 + vu * 32;
#pragma unroll
    for (int k = 0; k < 4; ++k) vpre[k] = *(const bf16x8*)(vs + 8 * k);
  };
  auto stKV = [&](int bb) {
#pragma unroll
    for (int k = 0; k < 4; ++k) *(bf16x8*)&Kl[bb][ks_][kd0 + 8 * k] = kpre[k];
#pragma unroll
    for (int k = 0; k < 4; ++k) {
      int g = (4 * vu + k) ^ vxw;             // swizzled 8-elem granule
      *(bf16x8*)&Vl[bb][vd_ * VST + (g << 3)] = vpre[k];
    }
  };

  auto compute = [&](int t, int bb) {
    // ---- QK^T (swapped): S^T rows s = t*64+m*16+lg*4+r, col q = n*16+lq ----
    f32x4 accS[4][2];
#pragma unroll
    for (int m = 0; m < 4; ++m)
#pragma unroll
      for (int n = 0; n < 2; ++n) accS[m][n] = zero;
    __builtin_amdgcn_s_setprio(1);
#pragma unroll
    for (int m = 0; m < 4; ++m) {
      bf16x8 ak[4];
#pragma unroll
      for (int kk = 0; kk < 4; ++kk)
        ak[kk] = *(const bf16x8*)&Kl[bb][m * 16 + lq][kk * 32 + lg * 8];
#pragma unroll
      for (int n = 0; n < 2; ++n)
#pragma unroll
        for (int kk = 0; kk < 4; ++kk)
          accS[m][n] = __builtin_amdgcn_mfma_f32_16x16x32_bf16(ak[kk], qf[n][kk], accS[m][n], 0, 0, 0);
    }
    __builtin_amdgcn_s_setprio(0);

    // ---- causal mask (boundary tiles only) ----
    if (t * KVB + KVB - 1 > ctx + lb) {
#pragma unroll
      for (int m = 0; m < 4; ++m) {
        int sg = t * 64 + m * 16 + lg * 4;
#pragma unroll
        for (int n = 0; n < 2; ++n) {
          int qpos = ctx + lb + n * 16 + lq;
#pragma unroll
          for (int r = 0; r < 4; ++r)
            if (sg + r > qpos) accS[m][n][r] = -1e30f;
        }
      }
    }

    // ---- online softmax (per q column = lane&15), defer-max ----
#pragma unroll
    for (int n = 0; n < 2; ++n) {
      float mx = accS[0][n][0];
#pragma unroll
      for (int m = 0; m < 4; ++m)
#pragma unroll
        for (int r = 0; r < 4; ++r) mx = fmaxf(mx, accS[m][n][r]);
      mx = fmaxf(mx, __shfl_xor(mx, 16));
      mx = fmaxf(mx, __shfl_xor(mx, 32));
      if (!__all(mx <= mrun[n] + TH8)) {
        float mnew = fmaxf(mrun[n], mx);
        float corr = exp2f((mrun[n] - mnew) * CEXP);
        mrun[n] = mnew;
        lrun[n] *= corr;
        float cb[4];
#pragma unroll
        for (int r = 0; r < 4; ++r) cb[r] = __shfl(corr, lg * 4 + r);
#pragma unroll
        for (int nd = 0; nd < 8; ++nd)
#pragma unroll
          for (int r = 0; r < 4; ++r) accO[n][nd][r] *= cb[r];
      }
      float psum = 0.f;
#pragma unroll
      for (int m = 0; m < 4; ++m)
#pragma unroll
        for (int r = 0; r < 4; ++r) {
          float p = exp2f((accS[m][n][r] - mrun[n]) * CEXP);
          psum += p;
          accS[m][n][r] = p;
        }
      lrun[n] += psum;
    }

    // ---- k-permuted A-fragment: slot j of (n,ks) holds
    // P[s = 32ks + 16(j>>2) + 4lg + (j&3)] = accS[2ks + (j>>2)][n][j&3]. ----
    bf16x8 ap[2][2];
#pragma unroll
    for (int n = 0; n < 2; ++n)
#pragma unroll
      for (int ks3 = 0; ks3 < 2; ++ks3) {
#pragma unroll
        for (int e = 0; e < 4; ++e) {
          ap[n][ks3][e]     = (bf16)accS[2 * ks3][n][e];
          ap[n][ks3][4 + e] = (bf16)accS[2 * ks3 + 1][n][e];
        }
      }

    // ---- PV: B slot j of ks = V[s=pi(k)][d], read from swizzled Vl ----
    __builtin_amdgcn_s_setprio(1);
#pragma unroll
    for (int nd = 0; nd < 8; ++nd) {
      int d   = nd * 16 + lq;
      int vxr = ((d >> 3) & 3) << 1;
      int rb  = d * VST + 4 * (lg & 1);
#pragma unroll
      for (int ks3 = 0; ks3 < 2; ++ks3) {
        int g0 = 4 * ks3 + (lg >> 1);
        bf16x4 lo = *(const bf16x4*)&Vl[bb][rb + ((g0 ^ vxr) << 3)];
        bf16x4 hi2 = *(const bf16x4*)&Vl[bb][rb + (((g0 + 2) ^ vxr) << 3)];
        bf16x8 bv;
#pragma unroll
        for (int e = 0; e < 4; ++e) { bv[e] = lo[e]; bv[4 + e] = hi2[e]; }
#pragma unroll
        for (int n = 0; n < 2; ++n)
          accO[n][nd] = __builtin_amdgcn_mfma_f32_16x16x32_bf16(ap[n][ks3], bv, accO[n][nd], 0, 0, 0);
      }
    }
    __builtin_amdgcn_s_setprio(0);
  };

  if (WS) {
    ldKV(0);
    stKV(0);
    if (nt > 1) ldKV(1);
    __syncthreads();
    for (int t = 0; t < nt; ++t) {
      int cur = t & 1;
      if (t + 1 < nt) {
        stKV(cur ^ 1);                 // store t+1 (loads issued last iter)
        if (t + 2 < nt) ldKV(t + 2);
      }
      compute(t, cur);
      __syncthreads();                 // single barrier per tile
    }
  } else {
    for (int t = 0; t < nt; ++t) {
      {
        int s  = tid >> 2;
        int d0 = (tid & 3) * 32;
        int pb = btr[t * 2 + (s >> 5)];
        const float* ksrc = kc + (((size_t)pb * 32 + (s & 31)) * 8 + h) * 128 + d0;
#pragma unroll
        for (int k = 0; k < 4; ++k) {
          float4 a = *(const float4*)(ksrc + 8 * k);
          float4 c2 = *(const float4*)(ksrc + 8 * k + 4);
          *(bf16x8*)&Kl[0][s][d0 + 8 * k] = cvt8(a, c2);
        }
        int d  = tid & 127;
        int sh = tid >> 7;
        int vxf = ((d >> 3) & 3) << 1;
        int pbv = btr[t * 2 + sh];
        const float* vsrc = vc + (((size_t)pbv * 32) * 8 + h) * 128 + d;
#pragma unroll
        for (int k = 0; k < 8; ++k) {
          bf16x4 o;
#pragma unroll
          for (int j = 0; j < 4; ++j) o[j] = (bf16)vsrc[(size_t)(k * 4 + j) * 1024];
          int g = (4 * sh + (k >> 1)) ^ vxf;
          *(bf16x4*)&Vl[0][d * VST + (g << 3) + 4 * (k & 1)] = o;
        }
      }
      __syncthreads();
      compute(t, 0);
      __syncthreads();
    }
  }

  // ---- epilogue: finish row sums, normalize, store f32 ----
#pragma unroll
  for (int n = 0; n < 2; ++n) {
    lrun[n] += __shfl_xor(lrun[n], 16);
    lrun[n] += __shfl_xor(lrun[n], 32);
    lrun[n] = 1.f / lrun[n];
  }
#pragma unroll
  for (int m2 = 0; m2 < 2; ++m2) {
    float rb[4];
#pragma unroll
    for (int r = 0; r < 4; ++r) rb[r] = __shfl(lrun[m2], lg * 4 + r);
#pragma unroll
    for (int r = 0; r < 4; ++r) {
      float* op = out + (((size_t)(b * LQ + lb + m2 * 16 + lg * 4 + r)) * HQN + hq) * DH + lq;
#pragma unroll
      for (int nd = 0; nd < 8; ++nd) op[nd * 16] = accO[m2][nd][r] * rb[r];
    }
  }
}

extern "C" void kernel_launch(void* const* d_in, const int* in_sizes, int n_in,
                              void* d_out, int out_size, void* d_ws, size_t ws_size,
                              hipStream_t stream) {
  const float* q  = (const float*)d_in[0];
  const float* kc = (const float*)d_in[1];
  const float* vc = (const float*)d_in[2];
  const int* bt   = (const int*)d_in[3];
  const int* sl   = (const int*)d_in[4];
  float* out = (float*)d_out;

  size_t half = (size_t)NSEQ * HKVN * SKV * DH;
  size_t need = 2 * half * sizeof(bf16);
  if (ws_size >= need) {
    bf16* kb = (bf16*)d_ws;
    bf16* vt = kb + half;
    hipLaunchKernelGGL(prep_k, dim3(4096), dim3(256), 0, stream, kc, bt, kb);
    hipLaunchKernelGGL(prep_vt, dim3(1024), dim3(256), 0, stream, vc, bt, vt);
    hipLaunchKernelGGL((attn_kern<true>), dim3(512), dim3(256), 0, stream,
                       q, kc, vc, bt, sl, kb, vt, out);
  } else {
    hipLaunchKernelGGL((attn_kern<false>), dim3(512), dim3(256), 0, stream,
                       q, kc, vc, bt, sl, (const bf16*)nullptr, (const bf16*)nullptr, out);
  }
}